// Round 2
// baseline (7721.315 us; speedup 1.0000x reference)
//
#include <hip/hip_runtime.h>
#include <math.h>

// ---------------------------------------------------------------------------
// Spiking transformer block — fp64-exact up to every spike decision.
//  * IF node w/ constant input y: 10-step loop reproduces spike train exactly.
//  * GQA tile: head h -> kv head (h%8); 4 identical repeats => xa = 0.5*S8.V8
//    (integer-exact). Attention output channel c = d*32 + h.
//  * QKV GEMMs emit bit-packed spike patterns (pos lo16 | neg hi16).
//  * w1/w3 GEMMs emit 8-bit spike counts; w2 GEMM fuses s1*s3 + residual.
// ---------------------------------------------------------------------------

__device__ __forceinline__ unsigned spike_pat_d(double y) {
    double v = 0.0; unsigned p = 0u;
#pragma unroll
    for (int t = 0; t < 10; ++t) {
        v += y;
        bool s = (v >= 1.0);
        p |= s ? (1u << t) : 0u;
        v = s ? 0.0 : v;
    }
    return p;
}

__device__ __forceinline__ int spike_count_d(double y) {
    double v = 0.0; int c = 0;
#pragma unroll
    for (int t = 0; t < 10; ++t) {
        v += y;
        bool s = (v >= 1.0);
        c += s ? 1 : 0;
        v = s ? 0.0 : v;
    }
    return c;
}

// ----------------------------- RMSNorm (f32 in -> f64 out) -----------------
__global__ __launch_bounds__(256) void rms_f_kernel(const float* __restrict__ x,
                                                    const float* __restrict__ w,
                                                    double* __restrict__ out)
{
    const int row = blockIdx.x, tid = threadIdx.x;
    const float4* xr = (const float4*)(x + (size_t)row * 4096);
    const float4* wr = (const float4*)w;
    double* orow = out + (size_t)row * 4096;
    float4 v[4];
    double ss = 0.0;
#pragma unroll
    for (int i = 0; i < 4; ++i) {
        v[i] = xr[tid + (i << 8)];
        ss += (double)v[i].x * v[i].x + (double)v[i].y * v[i].y +
              (double)v[i].z * v[i].z + (double)v[i].w * v[i].w;
    }
#pragma unroll
    for (int off = 32; off > 0; off >>= 1) ss += __shfl_down(ss, off, 64);
    __shared__ double red[4];
    if ((tid & 63) == 0) red[tid >> 6] = ss;
    __syncthreads();
    double m = (red[0] + red[1] + red[2] + red[3]) * (1.0 / 4096.0);
    double sc = 1.0 / sqrt(m + 1e-5);
#pragma unroll
    for (int i = 0; i < 4; ++i) {
        float4 wv = wr[tid + (i << 8)];
        int b = (tid + (i << 8)) << 2;
        orow[b + 0] = ((double)v[i].x * sc) * (double)wv.x;
        orow[b + 1] = ((double)v[i].y * sc) * (double)wv.y;
        orow[b + 2] = ((double)v[i].z * sc) * (double)wv.z;
        orow[b + 3] = ((double)v[i].w * sc) * (double)wv.w;
    }
}

// ----------------------------- RMSNorm (f64 in -> f64 out) -----------------
__global__ __launch_bounds__(256) void rms_d_kernel(const double* __restrict__ x,
                                                    const float* __restrict__ w,
                                                    double* __restrict__ out)
{
    const int row = blockIdx.x, tid = threadIdx.x;
    const double2* xr = (const double2*)(x + (size_t)row * 4096);
    const float2* wr = (const float2*)w;
    double* orow = out + (size_t)row * 4096;
    double2 v[8];
    double ss = 0.0;
#pragma unroll
    for (int i = 0; i < 8; ++i) {
        v[i] = xr[tid + (i << 8)];
        ss += v[i].x * v[i].x + v[i].y * v[i].y;
    }
#pragma unroll
    for (int off = 32; off > 0; off >>= 1) ss += __shfl_down(ss, off, 64);
    __shared__ double red[4];
    if ((tid & 63) == 0) red[tid >> 6] = ss;
    __syncthreads();
    double m = (red[0] + red[1] + red[2] + red[3]) * (1.0 / 4096.0);
    double sc = 1.0 / sqrt(m + 1e-5);
#pragma unroll
    for (int i = 0; i < 8; ++i) {
        float2 wv = wr[tid + (i << 8)];
        int b = (tid + (i << 8)) << 1;
        orow[b + 0] = (v[i].x * sc) * (double)wv.x;
        orow[b + 1] = (v[i].y * sc) * (double)wv.y;
    }
}

// ----------------------------- GEMM ----------------------------------------
// C[m,n] = sum_k A[m,k]*W[n,k]  (NT, K-contiguous). fp64 accumulate.
// MODE 0: A f64, dual relu -> pattern u32 (pos lo16 | neg hi16)   (QKV)
// MODE 1: A f64, dual relu -> s3 int8  = cnt(yp)-cnt(yn)           (w3)
// MODE 2: A f64, pos relu  -> s1 uint8 = cnt(yp)                   (w1)
// MODE 3: A f64 plain, ADD f32 -> C f64 = ADD + acc                (wo)
// MODE 4: A = (s1/10)*(s3/10) from u8/i8, ADD f64 -> C f32         (w2)
template <int MODE>
__global__ __launch_bounds__(256) void gemm_kernel(
    const void* __restrict__ Av, const void* __restrict__ A2v,
    const float* __restrict__ W, const void* __restrict__ ADDv,
    void* __restrict__ C0v, int K, int N)
{
    constexpr bool DUAL = (MODE == 0 || MODE == 1);
    constexpr int NB = DUAL ? 2 : 1;
    __shared__ __align__(16) double As[NB][16][68];
    __shared__ __align__(16) float Ws[16][68];
    const int tid = threadIdx.x;
    const int tx = tid & 15, ty = tid >> 4;
    const int m0 = blockIdx.y << 6, n0 = blockIdx.x << 6;
    const int lrow = tid >> 2;          // 0..63
    const int lk = (tid & 3) << 2;      // 0,4,8,12

    double accp[4][4] = {};
    double accn[4][4] = {};

    const float* Wpt = W + (size_t)(n0 + lrow) * K + lk;
    const double* Apt = nullptr;
    const unsigned char* S1t = nullptr;
    const signed char* S3t = nullptr;
    if constexpr (MODE <= 3) {
        Apt = (const double*)Av + (size_t)(m0 + lrow) * K + lk;
    } else {
        S1t = (const unsigned char*)Av + (size_t)(m0 + lrow) * K + lk;
        S3t = (const signed char*)A2v + (size_t)(m0 + lrow) * K + lk;
    }

    for (int k0 = 0; k0 < K; k0 += 16) {
        double a[4];
        if constexpr (MODE <= 3) {
            double2 a01 = *(const double2*)(Apt + k0);
            double2 a23 = *(const double2*)(Apt + k0 + 2);
            a[0] = a01.x; a[1] = a01.y; a[2] = a23.x; a[3] = a23.y;
        } else {
            uchar4 c1 = *(const uchar4*)(S1t + k0);
            char4  c3 = *(const char4*)(S3t + k0);
            a[0] = ((double)c1.x * 0.1) * ((double)c3.x * 0.1);
            a[1] = ((double)c1.y * 0.1) * ((double)c3.y * 0.1);
            a[2] = ((double)c1.z * 0.1) * ((double)c3.z * 0.1);
            a[3] = ((double)c1.w * 0.1) * ((double)c3.w * 0.1);
        }
        float4 wv = *(const float4*)(Wpt + k0);
        float wf[4] = {wv.x, wv.y, wv.z, wv.w};
#pragma unroll
        for (int j = 0; j < 4; ++j) {
            if constexpr (DUAL) {
                As[0][lk + j][lrow] = fmax(a[j], 0.0);
                As[1][lk + j][lrow] = fmax(-a[j], 0.0);
            } else if constexpr (MODE == 2) {
                As[0][lk + j][lrow] = fmax(a[j], 0.0);
            } else {
                As[0][lk + j][lrow] = a[j];
            }
            Ws[lk + j][lrow] = wf[j];
        }
        __syncthreads();
#pragma unroll
        for (int k = 0; k < 16; ++k) {
            double2 mp01 = *(const double2*)&As[0][k][ty << 2];
            double2 mp23 = *(const double2*)&As[0][k][(ty << 2) + 2];
            float4 nf = *(const float4*)&Ws[k][tx << 2];
            double mp[4] = {mp01.x, mp01.y, mp23.x, mp23.y};
            double nd[4] = {(double)nf.x, (double)nf.y, (double)nf.z, (double)nf.w};
            if constexpr (DUAL) {
                double2 mn01 = *(const double2*)&As[1][k][ty << 2];
                double2 mn23 = *(const double2*)&As[1][k][(ty << 2) + 2];
                double mn[4] = {mn01.x, mn01.y, mn23.x, mn23.y};
#pragma unroll
                for (int i = 0; i < 4; ++i)
#pragma unroll
                    for (int j2 = 0; j2 < 4; ++j2) {
                        accp[i][j2] = fma(mp[i], nd[j2], accp[i][j2]);
                        accn[i][j2] = fma(mn[i], nd[j2], accn[i][j2]);
                    }
            } else {
#pragma unroll
                for (int i = 0; i < 4; ++i)
#pragma unroll
                    for (int j2 = 0; j2 < 4; ++j2)
                        accp[i][j2] = fma(mp[i], nd[j2], accp[i][j2]);
            }
        }
        __syncthreads();
    }

#pragma unroll
    for (int i = 0; i < 4; ++i) {
        int m = m0 + (ty << 2) + i;
        size_t idx = (size_t)m * N + n0 + (tx << 2);
        if constexpr (MODE == 0) {
            uint4 o;
            o.x = spike_pat_d(accp[i][0]) | (spike_pat_d(accn[i][0]) << 16);
            o.y = spike_pat_d(accp[i][1]) | (spike_pat_d(accn[i][1]) << 16);
            o.z = spike_pat_d(accp[i][2]) | (spike_pat_d(accn[i][2]) << 16);
            o.w = spike_pat_d(accp[i][3]) | (spike_pat_d(accn[i][3]) << 16);
            *(uint4*)((unsigned*)C0v + idx) = o;
        } else if constexpr (MODE == 1) {
            char4 o;
            o.x = (signed char)(spike_count_d(accp[i][0]) - spike_count_d(accn[i][0]));
            o.y = (signed char)(spike_count_d(accp[i][1]) - spike_count_d(accn[i][1]));
            o.z = (signed char)(spike_count_d(accp[i][2]) - spike_count_d(accn[i][2]));
            o.w = (signed char)(spike_count_d(accp[i][3]) - spike_count_d(accn[i][3]));
            *(char4*)((signed char*)C0v + idx) = o;
        } else if constexpr (MODE == 2) {
            uchar4 o;
            o.x = (unsigned char)spike_count_d(accp[i][0]);
            o.y = (unsigned char)spike_count_d(accp[i][1]);
            o.z = (unsigned char)spike_count_d(accp[i][2]);
            o.w = (unsigned char)spike_count_d(accp[i][3]);
            *(uchar4*)((unsigned char*)C0v + idx) = o;
        } else if constexpr (MODE == 3) {
            const float* ADD = (const float*)ADDv;
            float4 ad = *(const float4*)(ADD + idx);
            double* C = (double*)C0v;
            C[idx + 0] = (double)ad.x + accp[i][0];
            C[idx + 1] = (double)ad.y + accp[i][1];
            C[idx + 2] = (double)ad.z + accp[i][2];
            C[idx + 3] = (double)ad.w + accp[i][3];
        } else {
            const double* ADD = (const double*)ADDv;
            float4 o;
            o.x = (float)(ADD[idx + 0] + accp[i][0]);
            o.y = (float)(ADD[idx + 1] + accp[i][1]);
            o.z = (float)(ADD[idx + 2] + accp[i][2]);
            o.w = (float)(ADD[idx + 3] + accp[i][3]);
            *(float4*)((float*)C0v + idx) = o;
        }
    }
}

// ----------------------------- Attention core ------------------------------
// One block per token. Patterns pre-packed (pos lo16 | neg hi16).
// S8[t][h][j8] integer-exact; xa = 0.5*S8.V8 (exact in fp32); out f64 /10.
__global__ __launch_bounds__(256) void attn_kernel(
    const unsigned* __restrict__ patq_g, const unsigned* __restrict__ patk_g,
    const unsigned* __restrict__ patv_g, double* __restrict__ Aout)
{
    __shared__ __align__(16) unsigned patq[4096];
    __shared__ __align__(16) unsigned patk[1024];
    __shared__ __align__(16) unsigned patv[1024];
    __shared__ int S8[10][32][8];
    const int n = blockIdx.x, tid = threadIdx.x;

    const uint4* q4 = (const uint4*)(patq_g + (size_t)n * 4096);
#pragma unroll
    for (int r = 0; r < 4; ++r)
        ((uint4*)patq)[tid + (r << 8)] = q4[tid + (r << 8)];
    ((uint4*)patk)[tid] = ((const uint4*)(patk_g + (size_t)n * 1024))[tid];
    ((uint4*)patv)[tid] = ((const uint4*)(patv_g + (size_t)n * 1024))[tid];
    __syncthreads();

    const int hi = tid >> 3;  // head 0..31
    const int j8 = tid & 7;   // kv-head (phase 1) / d-group (phase 2)

    int sacc[10] = {0, 0, 0, 0, 0, 0, 0, 0, 0, 0};
    for (int d = 0; d < 128; ++d) {
        unsigned q = patq[(hi << 7) + d];
        unsigned k = patk[(j8 << 7) + d];
        unsigned qp = q & 0xFFFFu, qn = q >> 16;
        unsigned kp = k & 0xFFFFu, kn = k >> 16;
        unsigned pos = (qp & kp) | (qn & kn);
        unsigned neg = (qp & kn) | (qn & kp);
#pragma unroll
        for (int t = 0; t < 10; ++t)
            sacc[t] += (int)((pos >> t) & 1u) - (int)((neg >> t) & 1u);
    }
#pragma unroll
    for (int t = 0; t < 10; ++t) S8[t][hi][j8] = sacc[t];
    __syncthreads();

    float xacc[16];
#pragma unroll
    for (int dd = 0; dd < 16; ++dd) xacc[dd] = 0.f;

    for (int t = 0; t < 10; ++t) {
        int s8r[8];
#pragma unroll
        for (int jj = 0; jj < 8; ++jj) s8r[jj] = S8[t][hi][jj];
#pragma unroll
        for (int dd = 0; dd < 16; ++dd) {
            int d = (j8 << 4) + dd;
            int acc = 0;
#pragma unroll
            for (int jj = 0; jj < 8; ++jj) {
                unsigned v = patv[(jj << 7) + d];
                int vv = (int)((v >> t) & 1u) - (int)((v >> (t + 16)) & 1u);
                acc += s8r[jj] * vv;
            }
            xacc[dd] += 0.5f * (float)acc;
        }
    }
#pragma unroll
    for (int dd = 0; dd < 16; ++dd) {
        int d = (j8 << 4) + dd;
        Aout[(size_t)n * 4096 + (d << 5) + hi] = (double)xacc[dd] / 10.0;
    }
}

// ----------------------------- Launch --------------------------------------
extern "C" void kernel_launch(void* const* d_in, const int* in_sizes, int n_in,
                              void* d_out, int out_size, void* d_ws, size_t ws_size,
                              hipStream_t stream)
{
    const float* x   = (const float*)d_in[0];
    const float* anw = (const float*)d_in[2];
    const float* fnw = (const float*)d_in[3];
    const float* wq  = (const float*)d_in[4];
    const float* wk  = (const float*)d_in[5];
    const float* wv  = (const float*)d_in[6];
    const float* wo  = (const float*)d_in[7];
    const float* w1  = (const float*)d_in[8];
    const float* w2  = (const float*)d_in[9];
    const float* w3  = (const float*)d_in[10];
    float* out = (float*)d_out;

    double* h1 = (double*)d_ws;            // 256x4096 f64
    double* Ap = h1 + 1048576;             // 256x4096 f64 (pooled attn, c=d*32+h)
    double* hb = Ap + 1048576;             // 256x4096 f64 residual h
    double* h2 = hb + 1048576;             // 256x4096 f64
    unsigned* patq = (unsigned*)(h2 + 1048576);  // 256x4096 u32
    unsigned* patk = patq + 1048576;             // 256x1024 u32
    unsigned* patv = patk + 262144;              // 256x1024 u32
    unsigned char* s1 = (unsigned char*)(patv + 262144);  // 256x14336 u8
    signed char*  s3 = (signed char*)(s1 + 3670016);      // 256x14336 i8
    // total ~45 MB of d_ws

    dim3 blk(256);
    rms_f_kernel<<<dim3(256), blk, 0, stream>>>(x, anw, h1);
    gemm_kernel<0><<<dim3(64, 4), blk, 0, stream>>>(h1, nullptr, wq, nullptr, patq, 4096, 4096);
    gemm_kernel<0><<<dim3(16, 4), blk, 0, stream>>>(h1, nullptr, wk, nullptr, patk, 4096, 1024);
    gemm_kernel<0><<<dim3(16, 4), blk, 0, stream>>>(h1, nullptr, wv, nullptr, patv, 4096, 1024);
    attn_kernel<<<dim3(256), blk, 0, stream>>>(patq, patk, patv, Ap);
    gemm_kernel<3><<<dim3(64, 4), blk, 0, stream>>>(Ap, nullptr, wo, x, hb, 4096, 4096);
    rms_d_kernel<<<dim3(256), blk, 0, stream>>>(hb, fnw, h2);
    gemm_kernel<1><<<dim3(224, 4), blk, 0, stream>>>(h2, nullptr, w3, nullptr, s3, 4096, 14336);
    gemm_kernel<2><<<dim3(224, 4), blk, 0, stream>>>(h2, nullptr, w1, nullptr, s1, 4096, 14336);
    gemm_kernel<4><<<dim3(64, 4), blk, 0, stream>>>(s1, s3, w2, hb, out, 14336, 4096);
}